// Round 1
// baseline (79.048 us; speedup 1.0000x reference)
//
#include <hip/hip_runtime.h>

#define N_TOTAL   4096
#define N_NODES   1024
#define N_MARBLES 3072
#define N_EATERS  64
#define EPS       1e-6f
#define BLOCK     256
#define JCHUNK    64                  // j's per force block
#define JCHUNKS   (N_TOTAL / JCHUNK) // 64

typedef float v2f __attribute__((ext_vector_type(2)));

// ---------------------------------------------------------------------------
// Kernel 1: partial accelerations, VOP3P-packed over two i-particles/thread.
// grid = (8, 64), block = 256 -> 512 blocks = 2 blocks/CU = 2 waves/SIMD.
// j is wave-uniform -> s_load_dwordx2 for pos; the scalar j-operand is
// broadcast into both packed halves (no repack shuffles). Per j we now pay
// 10 packed VALU + 2 v_rsq for TWO pair-interactions (was 18 VALU + 2 rsq).
// d2==0 pairs contribute exactly 0 (dx=dy=0, finite w), so no mask needed.
// ---------------------------------------------------------------------------
__global__ __launch_bounds__(BLOCK) void force_partial(
    const float2* __restrict__ pos2, const float* __restrict__ mass,
    float2* __restrict__ partial)
{
    const int i0 = blockIdx.x * (2 * BLOCK) + threadIdx.x;  // first particle
    const int i1 = i0 + BLOCK;                              // second particle
    const int j0 = blockIdx.y * JCHUNK;

    const float2 pA = pos2[i0];
    const float2 pB = pos2[i1];
    const v2f pix = { pA.x, pB.x };
    const v2f piy = { pA.y, pB.y };

    v2f ax = { 0.f, 0.f };
    v2f ay = { 0.f, 0.f };

#pragma unroll 16
    for (int j = j0; j < j0 + JCHUNK; ++j) {
        const float2 pj = pos2[j];               // uniform -> s_load_dwordx2
        const float  mj = mass[j];               // uniform -> s_load
        const v2f dx = pj.x - pix;               // v_pk_add (neg mod)
        const v2f dy = pj.y - piy;
        const v2f t  = dx * dx + (dy * dy + EPS);  // 2x v_pk_fma (contract)
        v2f r;
        r.x = rsqrtf(t.x);                       // v_rsq_f32
        r.y = rsqrtf(t.y);
        const v2f w = r * r * r * mj;            // 3x v_pk_mul
        ax += w * dx;                            // v_pk_fma
        ay += w * dy;                            // v_pk_fma
    }

    const int row = blockIdx.y * N_TOTAL;
    partial[row + i0] = make_float2(ax.x, ay.x);
    partial[row + i1] = make_float2(ax.y, ay.y);
}

// ---------------------------------------------------------------------------
// Kernel 2: integrate + eaten, fused. grid = 64 blocks x 256 threads; each
// block owns 64 particles. Wave t (of 4) sums partial chunks [16t, 16t+16)
// with coalesced float2 reads; LDS-reduce 4 -> 1; wave 0 does the Euler step
// and writes state_new. Marble blocks (16..63) additionally reduce the 64
// eater nodes' partials (L2-hot gathers, arithmetic order identical to the
// node blocks' own reduction -> bitwise-identical eater pos_new), wave 1
// integrates the eaters into LDS, then wave 0 does the 64-eater proximity
// check and writes the eaten flags.
// ---------------------------------------------------------------------------
__global__ __launch_bounds__(BLOCK) void integrate_eaten(
    const float2* __restrict__ pos2, const float2* __restrict__ vel2,
    const float2* __restrict__ partial, const float* __restrict__ dtp,
    const int* __restrict__ eater_idx, const float* __restrict__ eater_radius,
    float2* __restrict__ out2, float* __restrict__ out_eaten)
{
    __shared__ float2 red[4][64];
    __shared__ float2 ered[4][64];
    __shared__ float  exs[N_EATERS], eys[N_EATERS], er2s[N_EATERS];

    const int  lane       = threadIdx.x & 63;   // particle within block
    const int  w          = threadIdx.x >> 6;   // wave id 0..3
    const int  i          = blockIdx.x * 64 + lane;
    const bool marble_blk = (blockIdx.x >= N_NODES / 64);  // blocks 16..63

    // Own-particle partial reduction (identical to previous version).
    float ax = 0.f, ay = 0.f;
#pragma unroll 16
    for (int jc = w * 16; jc < w * 16 + 16; ++jc) {
        const float2 p = partial[jc * N_TOTAL + i];
        ax += p.x;
        ay += p.y;
    }
    red[w][lane] = make_float2(ax, ay);

    // Marble blocks: redundantly reduce the 64 eater nodes' partials.
    int q = 0;
    if (marble_blk) {
        q = eater_idx[lane];
        float bx = 0.f, by = 0.f;
#pragma unroll 16
        for (int jc = w * 16; jc < w * 16 + 16; ++jc) {
            const float2 p = partial[jc * N_TOTAL + q];  // gather, L2-hot
            bx += p.x;
            by += p.y;
        }
        ered[w][lane] = make_float2(bx, by);
    }
    __syncthreads();

    const float dt = dtp[0];
    float px = 0.f, py = 0.f;

    if (w == 0) {
        const float2 r1 = red[1][lane];
        const float2 r2 = red[2][lane];
        const float2 r3 = red[3][lane];
        ax += r1.x + r2.x + r3.x;
        ay += r1.y + r2.y + r3.y;

        const float2 v = vel2[i];
        const float2 p = pos2[i];
        const float vx = v.x + ax * dt;
        const float vy = v.y + ay * dt;
        px = p.x + vx * dt;
        py = p.y + vy * dt;

        out2[i]           = make_float2(px, py);  // pos_new
        out2[N_TOTAL + i] = make_float2(vx, vy);  // vel_new
    }

    if (marble_blk && w == 1) {
        // Same summation order as the node blocks (e0 first, then 1,2,3).
        const float eax = ered[0][lane].x + ered[1][lane].x +
                          ered[2][lane].x + ered[3][lane].x;
        const float eay = ered[0][lane].y + ered[1][lane].y +
                          ered[2][lane].y + ered[3][lane].y;
        const float2 ev = vel2[q];
        const float2 ep = pos2[q];
        const float evx = ev.x + eax * dt;
        const float evy = ev.y + eay * dt;
        exs[lane] = ep.x + evx * dt;
        eys[lane] = ep.y + evy * dt;
        const float r = eater_radius[lane];
        er2s[lane] = r * r;
    }
    __syncthreads();

    if (marble_blk && w == 0) {
        bool any = false;
#pragma unroll
        for (int e = 0; e < N_EATERS; ++e) {
            const float dx = px - exs[e];
            const float dy = py - eys[e];
            any = any || (dx * dx + dy * dy <= er2s[e]);
        }
        out_eaten[i - N_NODES] = any ? 1.0f : 0.0f;
    }
}

extern "C" void kernel_launch(void* const* d_in, const int* in_sizes, int n_in,
                              void* d_out, int out_size, void* d_ws, size_t ws_size,
                              hipStream_t stream) {
    const float* pos  = (const float*)d_in[0];   // (4096, 2)
    const float* vel  = (const float*)d_in[1];   // (4096, 2)
    const float* mass = (const float*)d_in[2];   // (4096,)
    const int*   eidx = (const int*)d_in[3];     // (64,)
    const float* erad = (const float*)d_in[4];   // (64,)
    const float* dt   = (const float*)d_in[5];   // (1,)

    float* out      = (float*)d_out;             // 16384 state + 3072 eaten
    float2* partial = (float2*)d_ws;             // 64*4096 float2 = 2 MB

    dim3 g1(N_TOTAL / (2 * BLOCK), JCHUNKS);     // (8, 64)
    force_partial<<<g1, BLOCK, 0, stream>>>((const float2*)pos, mass, partial);
    integrate_eaten<<<N_TOTAL / 64, BLOCK, 0, stream>>>(
        (const float2*)pos, (const float2*)vel, partial, dt,
        eidx, erad, (float2*)out, out + 4 * N_TOTAL);
}